// Round 1
// baseline (242.636 us; speedup 1.0000x reference)
//
#include <hip/hip_runtime.h>
#include <cmath>

// FSEncLoss on gfx950.
// loss = mean over (block, c) of [ t*softplus(-x) + (1-t)*softplus(x) ]
//      = mean of [ softplus(x) - t*x ],  t = 1 iff class c appears in the 8x8 block.
//
// B=16, H=1024, W=2048, G=8, NUM_CLASSES=19 (fixed by setup_inputs()).
// Each workgroup (256 threads) covers an 8-row x 1024-col strip = 128 blocks.
// Thread t: 8 x int4 coalesced target loads (its 4 columns over 8 rows) ->
// 19-bit class-presence mask; pair-merge via shfl_xor(1) so lanes {2j,2j+1}
// both hold block j's mask; even lane sums classes 0..9, odd 10..18 of that
// block's preds row. Wave shfl reduction -> LDS across 4 waves -> one scaled
// atomicAdd per workgroup.

#define NCLS 19

__global__ __launch_bounds__(256) void fsenc_loss_kernel(
    const float* __restrict__ preds,
    const int*   __restrict__ targets,
    float*       __restrict__ out,
    int B, int H, int W, float inv_count)
{
    const int t  = threadIdx.x;
    const int wg = blockIdx.x;

    const int strips_per_row = W / 1024;          // 2
    const int rows_per_img   = H / 8;             // 128
    const int block_row = wg / strips_per_row;    // 0 .. B*H/8-1
    const int strip     = wg % strips_per_row;
    const int b_img = block_row / rows_per_img;
    const int bh    = block_row % rows_per_img;
    const int col0  = strip * 1024;

    // ---- targets: build per-column class mask over 8 rows, int4 loads ----
    const int4* tgt4 = (const int4*)targets;
    const long row_stride4 = (long)W / 4;
    long base = ((long)(b_img * H + bh * 8) * W + col0) / 4 + t;

    unsigned mask = 0u;
    #pragma unroll
    for (int r = 0; r < 8; ++r) {
        int4 v = tgt4[base + (long)r * row_stride4];
        mask |= (1u << v.x) | (1u << v.y) | (1u << v.z) | (1u << v.w);
    }
    // merge the two threads covering the same 8-wide block
    mask |= __shfl_xor(mask, 1);

    // ---- preds: softplus(x) - present*x over this block's 19 classes ----
    const int wpr = W / 8;                        // blocks per image row = 256
    const long blk = (long)(b_img * rows_per_img + bh) * wpr
                   + strip * 128 + (t >> 1);
    const float* row = preds + blk * NCLS;

    const int c0 = (t & 1) ? 10 : 0;
    const int c1 = (t & 1) ? NCLS : 10;
    float acc = 0.f;
    #pragma unroll
    for (int c = c0; c < c1; ++c) {
        float x  = row[c];
        float sp = fmaxf(x, 0.f) + log1pf(expf(-fabsf(x)));  // stable softplus
        acc += sp - (((mask >> c) & 1u) ? x : 0.f);
    }

    // ---- reduce: wave (64) -> workgroup -> one atomic ----
    #pragma unroll
    for (int off = 32; off; off >>= 1)
        acc += __shfl_down(acc, off);

    __shared__ float s[4];
    if ((t & 63) == 0) s[t >> 6] = acc;
    __syncthreads();
    if (t == 0) {
        float tot = s[0] + s[1] + s[2] + s[3];
        atomicAdd(out, tot * inv_count);
    }
}

extern "C" void kernel_launch(void* const* d_in, const int* in_sizes, int n_in,
                              void* d_out, int out_size, void* d_ws, size_t ws_size,
                              hipStream_t stream) {
    const float* preds   = (const float*)d_in[0];
    const int*   targets = (const int*)d_in[1];
    float*       out     = (float*)d_out;

    const int B = 16, H = 1024, W = 2048;
    // mean over n_blocks * NUM_CLASSES == in_sizes[0] (preds element count)
    const float inv_count = 1.0f / (float)in_sizes[0];

    hipMemsetAsync(out, 0, sizeof(float), stream);

    const int grid = B * (H / 8) * (W / 1024);   // 4096 workgroups
    fsenc_loss_kernel<<<grid, 256, 0, stream>>>(preds, targets, out,
                                                B, H, W, inv_count);
}

// Round 2
// 230.298 us; speedup vs baseline: 1.0536x; 1.0536x over previous
//
#include <hip/hip_runtime.h>
#include <cmath>

// FSEncLoss on gfx950.
// loss = mean over (block, c) of [ softplus(x) - t*x ],
//   t = 1 iff class c appears in the 8x8 target block.
//
// B=16, H=1024, W=2048, G=8, NUM_CLASSES=19 (fixed by setup_inputs()).
//
// Workgroup wg (256 threads) covers an 8-row x 1024-col target strip =
// 128 blocks == block indices [wg*128, wg*128+128), whose preds form a
// CONTIGUOUS 16B-aligned slab of 128*19 = 2432 floats = 608 float4.
//
// Phase 1 (targets): thread t does 8 coalesced int4 loads (4 cols x 8 rows)
//   -> 19-bit presence mask; shfl_xor(1) merges the lane pair covering one
//   8-wide block; even lane writes mask to LDS s_mask[128].
// Phase 2 (preds): threads stride the 608 float4s (fully coalesced, 16B);
//   per component, block_local = l/19 via magic mul, mask bit from LDS,
//   softplus via fast v_exp_f32/v_log_f32: max(x,0)+log(1+exp(-|x|)).
// Reduce: wave shfl -> LDS across 4 waves -> one scaled atomicAdd per WG.

#define NCLS 19

__global__ __launch_bounds__(256) void fsenc_loss_kernel(
    const float* __restrict__ preds,
    const int*   __restrict__ targets,
    float*       __restrict__ out,
    int B, int H, int W, float inv_count)
{
    const int t  = threadIdx.x;
    const int wg = blockIdx.x;

    __shared__ unsigned s_mask[128];
    __shared__ float s_part[4];

    // ---------- phase 1: targets -> per-block class presence mask ----------
    const int strips_per_row = W / 1024;          // 2
    const int rows_per_img   = H / 8;             // 128
    const int block_row = wg / strips_per_row;
    const int strip     = wg % strips_per_row;
    const int b_img = block_row / rows_per_img;
    const int bh    = block_row % rows_per_img;
    const int col0  = strip * 1024;

    const int4* tgt4 = (const int4*)targets;
    const long row_stride4 = (long)W / 4;
    long base = ((long)(b_img * H + bh * 8) * W + col0) / 4 + t;

    unsigned mask = 0u;
    #pragma unroll
    for (int r = 0; r < 8; ++r) {
        int4 v = tgt4[base + (long)r * row_stride4];
        mask |= (1u << v.x) | (1u << v.y) | (1u << v.z) | (1u << v.w);
    }
    mask |= __shfl_xor(mask, 1);          // lanes {2j,2j+1} -> block j's mask
    if ((t & 1) == 0) s_mask[t >> 1] = mask;
    __syncthreads();

    // ---------- phase 2: preds slab, coalesced float4 ----------
    // slab: 2432 floats starting at float index wg*2432 (byte offset wg*9728,
    // 16B-aligned). 608 float4s.
    const float4* p4 = (const float4*)(preds + (long)wg * 2432);

    float acc = 0.f;
    for (int i = t; i < 608; i += 256) {
        float4 v = p4[i];
        const unsigned l0 = (unsigned)i * 4u;   // local float index of v.x
        float xs[4] = {v.x, v.y, v.z, v.w};
        #pragma unroll
        for (int k = 0; k < 4; ++k) {
            unsigned l   = l0 + (unsigned)k;            // 0..2431
            unsigned blk = (l * 3450u) >> 16;           // l / 19 (exact, l<2432)
            unsigned c   = l - blk * 19u;
            float x  = xs[k];
            float sp = fmaxf(x, 0.f) + __logf(1.f + __expf(-fabsf(x)));
            float tf = (float)((s_mask[blk] >> c) & 1u);
            acc += sp - tf * x;
        }
    }

    // ---------- reduce: wave -> workgroup -> one atomic ----------
    #pragma unroll
    for (int off = 32; off; off >>= 1)
        acc += __shfl_down(acc, off);

    if ((t & 63) == 0) s_part[t >> 6] = acc;
    __syncthreads();
    if (t == 0) {
        float tot = s_part[0] + s_part[1] + s_part[2] + s_part[3];
        atomicAdd(out, tot * inv_count);
    }
}

extern "C" void kernel_launch(void* const* d_in, const int* in_sizes, int n_in,
                              void* d_out, int out_size, void* d_ws, size_t ws_size,
                              hipStream_t stream) {
    const float* preds   = (const float*)d_in[0];
    const int*   targets = (const int*)d_in[1];
    float*       out     = (float*)d_out;

    const int B = 16, H = 1024, W = 2048;
    const float inv_count = 1.0f / (float)in_sizes[0];   // n_blocks * 19

    hipMemsetAsync(out, 0, sizeof(float), stream);

    const int grid = B * (H / 8) * (W / 1024);   // 4096 workgroups
    fsenc_loss_kernel<<<grid, 256, 0, stream>>>(preds, targets, out,
                                                B, H, W, inv_count);
}

// Round 4
// 223.284 us; speedup vs baseline: 1.0867x; 1.0314x over previous
//
#include <hip/hip_runtime.h>
#include <cmath>

// FSEncLoss on gfx950.
// loss = mean over (block, c) of [ softplus(x) - t*x ],
//   t = 1 iff class c appears in the 8x8 target block.
// B=16, H=1024, W=2048, G=8, NUM_CLASSES=19 (fixed by setup_inputs()).
//
// Latency-bound problem (R2: HBM 14%, VALU 13%) -> maximize MLP, no barrier.
// Workgroup wg covers an 8-row x 1024-col strip = 128 blocks; lane pair
// (2j, 2j+1) owns strip-local block j:
//   targets: thread t loads int4 (4 cols) x 8 rows, coalesced (wave = 1KB/row);
//            mask OR + shfl_xor(1) -> both lanes hold block j's 19-bit mask.
//   preds:   block j's row = 19 floats at float offset (wg*128+j)*19.
//            even lane: x[0..7]  via 2 dword-aligned float4 loads (classes 0-7)
//            odd  lane: x[8..18] via 3 float4 loads (overlap at +15; classes 8-18)
// All ~11 loads per thread are independent -> deep VMEM pipeline, no
// __syncthreads until the final 4-partial reduce.
// softplus(x) = max(x,0) + log(1+exp(-|x|)) via v_exp_f32/v_log_f32.

typedef float uf4 __attribute__((vector_size(16), aligned(4)));  // dword-aligned float4

__global__ __launch_bounds__(256) void fsenc_loss_kernel(
    const float* __restrict__ preds,
    const int*   __restrict__ targets,
    float*       __restrict__ out,
    int B, int H, int W, float inv_count)
{
    const int t  = threadIdx.x;
    const int wg = blockIdx.x;

    // ---- targets: per-thread 4-col x 8-row mask, coalesced int4 ----
    const int strips_per_row = W / 1024;          // 2
    const int rows_per_img   = H / 8;             // 128
    const int block_row = wg / strips_per_row;
    const int strip     = wg % strips_per_row;
    const int b_img = block_row / rows_per_img;
    const int bh    = block_row % rows_per_img;
    const int col0  = strip * 1024;

    const int4* tgt4 = (const int4*)targets;
    const long row_stride4 = (long)W / 4;
    const long tbase = ((long)(b_img * H + bh * 8) * W + col0) / 4 + t;

    int4 tv[8];
    #pragma unroll
    for (int r = 0; r < 8; ++r)
        tv[r] = tgt4[tbase + (long)r * row_stride4];

    // ---- preds: issue this lane's loads (independent of targets) ----
    const long row = (long)wg * 2432 + (long)(t >> 1) * 19;  // block j = t>>1
    const float* p = preds + row;
    uf4 q0 = {0.f, 0.f, 0.f, 0.f}, q1 = q0, q2 = q0;
    if ((t & 1) == 0) {
        q0 = *(const uf4*)(p + 0);    // x[0..3]
        q1 = *(const uf4*)(p + 4);    // x[4..7]
    } else {
        q0 = *(const uf4*)(p + 8);    // x[8..11]
        q1 = *(const uf4*)(p + 12);   // x[12..15]
        q2 = *(const uf4*)(p + 15);   // x[15..18]; use [1],[2],[3]
    }

    // ---- build mask, merge lane pair ----
    unsigned mask = 0u;
    #pragma unroll
    for (int r = 0; r < 8; ++r)
        mask |= (1u << tv[r].x) | (1u << tv[r].y) | (1u << tv[r].z) | (1u << tv[r].w);
    mask |= __shfl_xor(mask, 1);      // lanes {2j,2j+1} -> block j's full mask

    // ---- softplus(x) - t*x over this lane's classes ----
    float acc = 0.f;
    #define SP_TERM(xval, cls)                                                 \
        {                                                                      \
            float x_ = (xval);                                                 \
            float sp_ = fmaxf(x_, 0.f) + __logf(1.f + __expf(-fabsf(x_)));     \
            acc += sp_ - (float)((mask >> (cls)) & 1u) * x_;                   \
        }
    if ((t & 1) == 0) {
        SP_TERM(q0[0], 0)  SP_TERM(q0[1], 1)  SP_TERM(q0[2], 2)  SP_TERM(q0[3], 3)
        SP_TERM(q1[0], 4)  SP_TERM(q1[1], 5)  SP_TERM(q1[2], 6)  SP_TERM(q1[3], 7)
    } else {
        SP_TERM(q0[0], 8)  SP_TERM(q0[1], 9)  SP_TERM(q0[2], 10) SP_TERM(q0[3], 11)
        SP_TERM(q1[0], 12) SP_TERM(q1[1], 13) SP_TERM(q1[2], 14) SP_TERM(q1[3], 15)
        SP_TERM(q2[1], 16) SP_TERM(q2[2], 17) SP_TERM(q2[3], 18)
    }
    #undef SP_TERM

    // ---- reduce: wave (64) -> workgroup -> one atomic ----
    #pragma unroll
    for (int off = 32; off; off >>= 1)
        acc += __shfl_down(acc, off);

    __shared__ float s_part[4];
    if ((t & 63) == 0) s_part[t >> 6] = acc;
    __syncthreads();
    if (t == 0) {
        float tot = s_part[0] + s_part[1] + s_part[2] + s_part[3];
        atomicAdd(out, tot * inv_count);
    }
}

extern "C" void kernel_launch(void* const* d_in, const int* in_sizes, int n_in,
                              void* d_out, int out_size, void* d_ws, size_t ws_size,
                              hipStream_t stream) {
    const float* preds   = (const float*)d_in[0];
    const int*   targets = (const int*)d_in[1];
    float*       out     = (float*)d_out;

    const int B = 16, H = 1024, W = 2048;
    const float inv_count = 1.0f / (float)in_sizes[0];   // n_blocks * 19

    (void)hipMemsetAsync(out, 0, sizeof(float), stream);

    const int grid = B * (H / 8) * (W / 1024);   // 4096 workgroups
    fsenc_loss_kernel<<<grid, 256, 0, stream>>>(preds, targets, out,
                                                B, H, W, inv_count);
}